// Round 2
// baseline (249.573 us; speedup 1.0000x reference)
//
#include <hip/hip_runtime.h>
#include <hip/hip_bf16.h>

#define BB 32
#define PP 1024
#define HID 512
#define NH 8
#define DD 64
#define MEM 64
#define RANK 64

// Workspace layout (floats)
#define A_OFF   0          // [8][64]
#define M_OFF   512        // [17][17]
#define T_OFF   1024       // [32][8][64]
#define G_OFF   18432      // [32][16][1024]
#define F_OFF   542720     // [32][17][1024]

// ---------------------------------------------------------------------------
// Kernel 1: tiny precompute. A[h][m] = w_k[h,:]·w_mem[m,:];
// WU[j][r]/WV[j][r] (17x64 each, in LDS); M17[i][j] = Σ_r WU[i][r]*WV[j][r].
// ---------------------------------------------------------------------------
__global__ __launch_bounds__(1024) void k_precompute(
    const float* __restrict__ wk, const float* __restrict__ wmem,
    const float* __restrict__ wv, const float* __restrict__ bv,
    const float* __restrict__ wu, const float* __restrict__ bu,
    const float* __restrict__ wv2, const float* __restrict__ bv2,
    float* __restrict__ A, float* __restrict__ M17) {
  __shared__ float WU[17 * 64];
  __shared__ float WV[17 * 64];
  const int t = threadIdx.x;

  if (t < 512) {
    const int h = t >> 6, m = t & 63;
    float s = 0.f;
    for (int d = 0; d < DD; ++d) s += wk[h * DD + d] * wmem[m * DD + d];
    A[t] = s;
  }

  for (int i = t; i < 17 * 64; i += 1024) {
    const int j = i >> 6, r = i & 63;
    float su = 0.f, sv = 0.f;
    if (j < 8) {
      for (int d = 0; d < DD; ++d) {
        const float w = wv[j * DD + d];
        su += wu[r * HID + j * DD + d] * w;
        sv += wv2[r * HID + j * DD + d] * w;
      }
    } else if (j < 16) {
      const int h = j - 8;
      for (int d = 0; d < DD; ++d) {
        const float w = bv[h * DD + d];
        su += wu[r * HID + h * DD + d] * w;
        sv += wv2[r * HID + h * DD + d] * w;
      }
    } else {
      su = bu[r];
      sv = bv2[r];
    }
    WU[i] = su;
    WV[i] = sv;
  }
  __syncthreads();

  if (t < 17 * 17) {
    const int i = t / 17, j = t % 17;
    float s = 0.f;
    for (int r = 0; r < 64; ++r) s += WU[i * 64 + r] * WV[j * 64 + r];
    M17[t] = s;
  }
}

// ---------------------------------------------------------------------------
// Kernel 2: T[b,h,m] = softmax_p(x[b,p]*A[h,m]) weighted mean of x.
// One wave per (b,h,m) task; 16384 tasks; 4 waves per block.
// ---------------------------------------------------------------------------
__global__ __launch_bounds__(256) void k_memsoftmax(
    const float* __restrict__ x, const float* __restrict__ A,
    float* __restrict__ T) {
  const int wid = blockIdx.x * 4 + (threadIdx.x >> 6);   // [0, 16384)
  const int lane = threadIdx.x & 63;
  const int b = wid >> 9;
  const int hm = wid & 511;               // h*64+m
  const float a = A[hm];
  const float* xr = x + b * PP;

  float xs[16];
  float mx = -INFINITY;
#pragma unroll
  for (int k = 0; k < 16; ++k) {
    xs[k] = xr[lane + k * 64];
    mx = fmaxf(mx, xs[k] * a);
  }
#pragma unroll
  for (int off = 32; off >= 1; off >>= 1) mx = fmaxf(mx, __shfl_xor(mx, off));

  float s = 0.f, sx = 0.f;
#pragma unroll
  for (int k = 0; k < 16; ++k) {
    const float e = __expf(xs[k] * a - mx);
    s += e;
    sx += e * xs[k];
  }
#pragma unroll
  for (int off = 32; off >= 1; off >>= 1) {
    s += __shfl_xor(s, off);
    sx += __shfl_xor(sx, off);
  }
  if (lane == 0) T[wid] = sx / s;
}

// ---------------------------------------------------------------------------
// Kernel 3 (fused tsums+features+fmap): one thread per (b,p).
//  - waves reduce T to S1/S2 (per block's b) in LDS
//  - per thread: loop 8 heads -> a1,a0 via 64-d ELU loop -> g[16] in regs
//  - F[j] = M17[16][j] + Σ_i g[i]*M17[i][j]; write G rows + F rows.
// Grid: 128 blocks x 256 threads; block n: b = n>>2, p = (n&3)*256 + t.
// ---------------------------------------------------------------------------
__global__ __launch_bounds__(256) void k_features_fused(
    const float* __restrict__ x, const float* __restrict__ wq,
    const float* __restrict__ bq, const float* __restrict__ wv,
    const float* __restrict__ bv, const float* __restrict__ T,
    const float* __restrict__ M17, float* __restrict__ G,
    float* __restrict__ F) {
  __shared__ float Ml[17 * 17];
  __shared__ float s1s[8], s2s[8];
  const int t = threadIdx.x;
  const int b = blockIdx.x >> 2;
  const int p = ((blockIdx.x & 3) << 8) + t;

  for (int i = t; i < 17 * 17; i += 256) Ml[i] = M17[i];

  const int w = t >> 6, lane = t & 63;
#pragma unroll
  for (int hh = w * 2; hh < w * 2 + 2; ++hh) {
    const float v = T[(b * 8 + hh) * MEM + lane];
    float s1 = v, s2 = v * v;
#pragma unroll
    for (int off = 32; off >= 1; off >>= 1) {
      s1 += __shfl_xor(s1, off);
      s2 += __shfl_xor(s2, off);
    }
    if (lane == 0) { s1s[hh] = s1; s2s[hh] = s2; }
  }
  __syncthreads();

  const float xv = x[b * PP + p];
  float g[16];
#pragma unroll
  for (int h = 0; h < 8; ++h) {
    float a1 = 0.f, a0 = 0.f;
#pragma unroll 8
    for (int d = 0; d < DD; ++d) {
      const float q = xv * wq[h * DD + d] + bq[h * DD + d];
      const float ph = (q > 0.f) ? (q + 1.f) : __expf(q);
      a1 += ph * wv[h * DD + d];
      a0 += ph * bv[h * DD + d];
    }
    const float s1 = s1s[h], s2 = s2s[h];
    g[h] = a1 * s2 + a0 * s1;
    g[8 + h] = a1 * s1 + a0 * (float)MEM;
  }

#pragma unroll
  for (int i = 0; i < 16; ++i) G[(b * 16 + i) * PP + p] = g[i];

#pragma unroll
  for (int j = 0; j < 17; ++j) {
    float f = Ml[16 * 17 + j];
#pragma unroll
    for (int i = 0; i < 16; ++i) f += g[i] * Ml[i * 17 + j];
    F[(b * 17 + j) * PP + p] = f;
  }
}

// ---------------------------------------------------------------------------
// Kernel 4: out[b,p,q] = F[b][16][p] + Σ_{j<16} F[b][j][p]*G[b][j][q].
// 128x128 tile per block, 256 threads, thread computes 8p x 8q.
// ---------------------------------------------------------------------------
__global__ __launch_bounds__(256) void k_coeffs(
    const float* __restrict__ F, const float* __restrict__ G,
    float* __restrict__ out) {
  __shared__ float Fl[17 * 128];
  __shared__ float Gl[16 * 128];
  const int b = blockIdx.z;
  const int p0 = blockIdx.y * 128;
  const int q0 = blockIdx.x * 128;
  const int t = threadIdx.x;

  const float* Fg = F + (size_t)b * 17 * PP;
  const float* Gg = G + (size_t)b * 16 * PP;
  for (int i = t; i < 17 * 128; i += 256) Fl[i] = Fg[(i >> 7) * PP + p0 + (i & 127)];
  for (int i = t; i < 16 * 128; i += 256) Gl[i] = Gg[(i >> 7) * PP + q0 + (i & 127)];
  __syncthreads();

  const int pr = (t >> 4) * 8;   // p offset within tile
  const int qc = (t & 15) * 8;   // q offset within tile

  float acc[8][8];
#pragma unroll
  for (int i = 0; i < 8; ++i) {
    const float f16v = Fl[16 * 128 + pr + i];
#pragma unroll
    for (int k = 0; k < 8; ++k) acc[i][k] = f16v;
  }

#pragma unroll
  for (int j = 0; j < 16; ++j) {
    float fj[8], gj[8];
    *(float4*)&fj[0] = *(const float4*)&Fl[j * 128 + pr];
    *(float4*)&fj[4] = *(const float4*)&Fl[j * 128 + pr + 4];
    *(float4*)&gj[0] = *(const float4*)&Gl[j * 128 + qc];
    *(float4*)&gj[4] = *(const float4*)&Gl[j * 128 + qc + 4];
#pragma unroll
    for (int i = 0; i < 8; ++i)
#pragma unroll
      for (int k = 0; k < 8; ++k) acc[i][k] += fj[i] * gj[k];
  }

#pragma unroll
  for (int i = 0; i < 8; ++i) {
    const size_t base = ((size_t)(b * PP + p0 + pr + i)) * PP + q0 + qc;
    *(float4*)&out[base] = make_float4(acc[i][0], acc[i][1], acc[i][2], acc[i][3]);
    *(float4*)&out[base + 4] = make_float4(acc[i][4], acc[i][5], acc[i][6], acc[i][7]);
  }
}

extern "C" void kernel_launch(void* const* d_in, const int* in_sizes, int n_in,
                              void* d_out, int out_size, void* d_ws, size_t ws_size,
                              hipStream_t stream) {
  const float* x    = (const float*)d_in[0];
  const float* wq   = (const float*)d_in[1];
  const float* bq   = (const float*)d_in[2];
  const float* wk   = (const float*)d_in[3];
  const float* bk   = (const float*)d_in[4];  (void)bk;  // drops out of softmax
  const float* wv   = (const float*)d_in[5];
  const float* bv   = (const float*)d_in[6];
  const float* wmem = (const float*)d_in[7];
  const float* wu   = (const float*)d_in[8];
  const float* bu   = (const float*)d_in[9];
  const float* wv2  = (const float*)d_in[10];
  const float* bv2  = (const float*)d_in[11];

  float* ws = (float*)d_ws;
  float* A   = ws + A_OFF;
  float* M17 = ws + M_OFF;
  float* T   = ws + T_OFF;
  float* G   = ws + G_OFF;
  float* F   = ws + F_OFF;
  float* out = (float*)d_out;

  k_precompute<<<1, 1024, 0, stream>>>(wk, wmem, wv, bv, wu, bu, wv2, bv2, A, M17);
  k_memsoftmax<<<4096, 256, 0, stream>>>(x, A, T);
  k_features_fused<<<128, 256, 0, stream>>>(x, wq, bq, wv, bv, T, M17, G, F);
  k_coeffs<<<dim3(8, 8, 32), 256, 0, stream>>>(F, G, out);
}

// Round 4
// 245.311 us; speedup vs baseline: 1.0174x; 1.0174x over previous
//
#include <hip/hip_runtime.h>
#include <hip/hip_bf16.h>

#define BB 32
#define PP 1024
#define HID 512
#define NH 8
#define DD 64
#define MEM 64
#define RANK 64

typedef float f32x4 __attribute__((ext_vector_type(4)));

// Workspace layout (floats)
#define T_OFF   1024       // [32][8][64]
#define G_OFF   18432      // [32][16][1024]
#define F_OFF   542720     // [32][17][1024]

// ---------------------------------------------------------------------------
// Kernel 1: T[b,h,m] = softmax_p(x[b,p]*A[h,m])-weighted mean of x,
// where A[h,m] = w_k[h,:]·w_mem[m,:] is computed inline by each wave
// (lane d holds one product, butterfly-reduce). One wave per (b,h,m);
// 16384 tasks; 4 waves per block.
// ---------------------------------------------------------------------------
__global__ __launch_bounds__(256) void k_memsoftmax(
    const float* __restrict__ x, const float* __restrict__ wk,
    const float* __restrict__ wmem, float* __restrict__ T) {
  const int wid = blockIdx.x * 4 + (threadIdx.x >> 6);   // [0, 16384)
  const int lane = threadIdx.x & 63;
  const int b = wid >> 9;
  const int hm = wid & 511;               // h*64+m
  const int h = hm >> 6, m = hm & 63;

  // inline A[h][m]
  float a = wk[h * DD + lane] * wmem[m * DD + lane];
#pragma unroll
  for (int off = 32; off >= 1; off >>= 1) a += __shfl_xor(a, off);

  const float* xr = x + b * PP;
  float xs[16];
  float mx = -INFINITY;
#pragma unroll
  for (int k = 0; k < 16; ++k) {
    xs[k] = xr[lane + k * 64];
    mx = fmaxf(mx, xs[k] * a);
  }
#pragma unroll
  for (int off = 32; off >= 1; off >>= 1) mx = fmaxf(mx, __shfl_xor(mx, off));

  float s = 0.f, sx = 0.f;
#pragma unroll
  for (int k = 0; k < 16; ++k) {
    const float e = __expf(xs[k] * a - mx);
    s += e;
    sx += e * xs[k];
  }
#pragma unroll
  for (int off = 32; off >= 1; off >>= 1) {
    s += __shfl_xor(s, off);
    sx += __shfl_xor(sx, off);
  }
  if (lane == 0) T[wid] = sx / s;
}

// ---------------------------------------------------------------------------
// Kernel 2 (fused M17+tsums+features+fmap): one thread per (b,p).
//  - block redundantly builds WU/WV (17x64) and M17 (17x17) in LDS
//  - waves reduce T to S1/S2 (per block's b) in LDS
//  - per thread: loop 8 heads -> a1,a0 via 64-d ELU loop -> g[16] in regs
//  - F[j] = M17[16][j] + sum_i g[i]*M17[i][j]; write G rows + F rows.
// Grid: 128 blocks x 256 threads; block n: b = n>>2, p = (n&3)*256 + t.
// ---------------------------------------------------------------------------
__global__ __launch_bounds__(256) void k_features_fused(
    const float* __restrict__ x, const float* __restrict__ wq,
    const float* __restrict__ bq, const float* __restrict__ wv,
    const float* __restrict__ bv, const float* __restrict__ wu,
    const float* __restrict__ bu, const float* __restrict__ wv2,
    const float* __restrict__ bv2, const float* __restrict__ T,
    float* __restrict__ G, float* __restrict__ F) {
  __shared__ float WU[17 * 64];
  __shared__ float WV[17 * 64];
  __shared__ float Ml[17 * 17];
  __shared__ float s1s[8], s2s[8];
  const int t = threadIdx.x;
  const int b = blockIdx.x >> 2;
  const int p = ((blockIdx.x & 3) << 8) + t;

  // WU[j][r] = wu[r,:hid] . basis_j ; basis_j = wv[j,:] (j<8), bv[j-8,:] (j<16)
  for (int i = t; i < 17 * 64; i += 256) {
    const int j = i >> 6, r = i & 63;
    float su, sv;
    if (j < 16) {
      const float* wrow = (j < 8) ? (wv + j * DD) : (bv + (j - 8) * DD);
      const int h = j & 7;
      const float* urow = wu + r * HID + h * DD;
      const float* vrow = wv2 + r * HID + h * DD;
      su = 0.f; sv = 0.f;
#pragma unroll
      for (int d = 0; d < DD; d += 4) {
        const float4 w4 = *(const float4*)&wrow[d];
        const float4 u4 = *(const float4*)&urow[d];
        const float4 v4 = *(const float4*)&vrow[d];
        su += u4.x * w4.x + u4.y * w4.y + u4.z * w4.z + u4.w * w4.w;
        sv += v4.x * w4.x + v4.y * w4.y + v4.z * w4.z + v4.w * w4.w;
      }
    } else {
      su = bu[r];
      sv = bv2[r];
    }
    WU[i] = su;
    WV[i] = sv;
  }

  // S1/S2 from T (independent of WU/WV, same barrier)
  {
    const int w = t >> 6, lane = t & 63;
#pragma unroll
    for (int hh = w * 2; hh < w * 2 + 2; ++hh) {
      const float v = T[(b * 8 + hh) * MEM + lane];
      float s1 = v, s2 = v * v;
#pragma unroll
      for (int off = 32; off >= 1; off >>= 1) {
        s1 += __shfl_xor(s1, off);
        s2 += __shfl_xor(s2, off);
      }
      if (lane == 0) { s1s[hh] = s1; s2s[hh] = s2; }
    }
  }
  __syncthreads();

  // M17[i][j] = sum_r WU[i][r]*WV[j][r]
  for (int ij = t; ij < 17 * 17; ij += 256) {
    const int i = ij / 17, j = ij % 17;
    float s = 0.f;
#pragma unroll
    for (int r = 0; r < 64; ++r) s += WU[i * 64 + r] * WV[j * 64 + r];
    Ml[ij] = s;
  }
  __syncthreads();

  const float xv = x[b * PP + p];
  float g[16];
#pragma unroll
  for (int h = 0; h < 8; ++h) {
    float a1 = 0.f, a0 = 0.f;
#pragma unroll 8
    for (int d = 0; d < DD; ++d) {
      const float q = xv * wq[h * DD + d] + bq[h * DD + d];
      const float ph = (q > 0.f) ? (q + 1.f) : __expf(q);
      a1 += ph * wv[h * DD + d];
      a0 += ph * bv[h * DD + d];
    }
    const float s1 = s1s[h], s2 = s2s[h];
    g[h] = a1 * s2 + a0 * s1;
    g[8 + h] = a1 * s1 + a0 * (float)MEM;
  }

#pragma unroll
  for (int i = 0; i < 16; ++i) G[(b * 16 + i) * PP + p] = g[i];

#pragma unroll
  for (int j = 0; j < 17; ++j) {
    float f = Ml[16 * 17 + j];
#pragma unroll
    for (int i = 0; i < 16; ++i) f += g[i] * Ml[i * 17 + j];
    F[(b * 17 + j) * PP + p] = f;
  }
}

// ---------------------------------------------------------------------------
// Kernel 3: out[b,p,q] = F[b][16][p] + sum_{j<16} F[b][j][p]*G[b][j][q].
// 128x128 tile per block, 256 threads, thread computes 8p x 8q.
// Nontemporal stores: output is write-once streaming, bypass L2.
// ---------------------------------------------------------------------------
__global__ __launch_bounds__(256) void k_coeffs(
    const float* __restrict__ F, const float* __restrict__ G,
    float* __restrict__ out) {
  __shared__ float Fl[17 * 128];
  __shared__ float Gl[16 * 128];
  const int b = blockIdx.z;
  const int p0 = blockIdx.y * 128;
  const int q0 = blockIdx.x * 128;
  const int t = threadIdx.x;

  const float* Fg = F + (size_t)b * 17 * PP;
  const float* Gg = G + (size_t)b * 16 * PP;
  for (int i = t; i < 17 * 128; i += 256) Fl[i] = Fg[(i >> 7) * PP + p0 + (i & 127)];
  for (int i = t; i < 16 * 128; i += 256) Gl[i] = Gg[(i >> 7) * PP + q0 + (i & 127)];
  __syncthreads();

  const int pr = (t >> 4) * 8;   // p offset within tile
  const int qc = (t & 15) * 8;   // q offset within tile

  float acc[8][8];
#pragma unroll
  for (int i = 0; i < 8; ++i) {
    const float f16v = Fl[16 * 128 + pr + i];
#pragma unroll
    for (int k = 0; k < 8; ++k) acc[i][k] = f16v;
  }

#pragma unroll
  for (int j = 0; j < 16; ++j) {
    float fj[8], gj[8];
    *(float4*)&fj[0] = *(const float4*)&Fl[j * 128 + pr];
    *(float4*)&fj[4] = *(const float4*)&Fl[j * 128 + pr + 4];
    *(float4*)&gj[0] = *(const float4*)&Gl[j * 128 + qc];
    *(float4*)&gj[4] = *(const float4*)&Gl[j * 128 + qc + 4];
#pragma unroll
    for (int i = 0; i < 8; ++i)
#pragma unroll
      for (int k = 0; k < 8; ++k) acc[i][k] += fj[i] * gj[k];
  }

#pragma unroll
  for (int i = 0; i < 8; ++i) {
    const size_t base = ((size_t)(b * PP + p0 + pr + i)) * PP + q0 + qc;
    f32x4 v0 = {acc[i][0], acc[i][1], acc[i][2], acc[i][3]};
    f32x4 v1 = {acc[i][4], acc[i][5], acc[i][6], acc[i][7]};
    __builtin_nontemporal_store(v0, (f32x4*)&out[base]);
    __builtin_nontemporal_store(v1, (f32x4*)&out[base + 4]);
  }
}

extern "C" void kernel_launch(void* const* d_in, const int* in_sizes, int n_in,
                              void* d_out, int out_size, void* d_ws, size_t ws_size,
                              hipStream_t stream) {
  const float* x    = (const float*)d_in[0];
  const float* wq   = (const float*)d_in[1];
  const float* bq   = (const float*)d_in[2];
  const float* wk   = (const float*)d_in[3];
  const float* bk   = (const float*)d_in[4];  (void)bk;  // drops out of softmax
  const float* wv   = (const float*)d_in[5];
  const float* bv   = (const float*)d_in[6];
  const float* wmem = (const float*)d_in[7];
  const float* wu   = (const float*)d_in[8];
  const float* bu   = (const float*)d_in[9];
  const float* wv2  = (const float*)d_in[10];
  const float* bv2  = (const float*)d_in[11];

  float* ws = (float*)d_ws;
  float* T   = ws + T_OFF;
  float* G   = ws + G_OFF;
  float* F   = ws + F_OFF;
  float* out = (float*)d_out;

  k_memsoftmax<<<4096, 256, 0, stream>>>(x, wk, wmem, T);
  k_features_fused<<<128, 256, 0, stream>>>(x, wq, bq, wv, bv, wu, bu, wv2,
                                            bv2, T, G, F);
  k_coeffs<<<dim3(8, 8, 32), 256, 0, stream>>>(F, G, out);
}